// Round 10
// baseline (550.334 us; speedup 1.0000x reference)
//
#include <hip/hip_runtime.h>

// GRU_43387759624777 — Round 10: two-group software pipeline (R9 + latency hiding).
//
// R9 post-mortem: 871 cyc/step = ~453 VALU (incl. 192 transcendental floor) +
// ~390 stall (barrier + ds_read 120 + MFMA + exp chain, nothing co-resident).
// Fix: the 16 batch rows are independent recurrences. Split into G0 (rows
// 0,1 mod 4) and G1 (rows 2,3 mod 4); 2-stage pipeline, one phase per group:
//   phase: barrier -> ds_read frag -> gates of the OTHER group (acc from the
//   previous phase; MFMA latency already paid) -> 6 MFMAs -> store h (2/lane).
// All 64 lanes do gate work every phase (group = D-reg halves r={0,1}/{2,3}).
// Single in-place A-frag buffer: MFMA row m depends only on A-frag row m, so
// concurrent rewrites of the other group's rows only corrupt D-rows that the
// consumer phase discards. Gate math hides the read latency; MFMA latency is
// hidden across the phase boundary. 2048 barriers, ~250-300 cyc each.
//
// Verified invariants (R3..R9): A-frag [m=lane&15][k=(lane>>4)*8+j]; C/D
// col=lane&15, row=(lane>>4)*4+reg; fp16 1-term MFMA + exp2-domain prescale
// (absmax 0.0 at R9); store (row m, unit u) -> hfrag[u>>5][m+16*((u>>3)&3)][u&7].

#define HID 64
#define SEQ 1024
#define BATCH 4096
#define ROWS 16
#define THREADS 256
#define NTB (SEQ / 64)

typedef __attribute__((ext_vector_type(8))) _Float16 half8;
typedef __attribute__((ext_vector_type(4))) float f32x4;

#define LOG2E 1.44269504088896340736f

__device__ __forceinline__ float rcp_fast(float x) { return __builtin_amdgcn_rcpf(x); }
__device__ __forceinline__ float exp2_fast(float x) { return __builtin_amdgcn_exp2f(x); }

__global__ __launch_bounds__(THREADS, 1) void gru_mfma(
    const float* __restrict__ x,     // [B, T]
    const float* __restrict__ w_ih,  // [192, 1]
    const float* __restrict__ w_hh,  // [192, 64]
    const float* __restrict__ b_ih,  // [192]
    const float* __restrict__ b_hh,  // [192]
    const float* __restrict__ w1,    // [32, 64]
    const float* __restrict__ b1,    // [32]
    const float* __restrict__ w2,    // [16, 32]
    const float* __restrict__ b2,    // [16]
    const float* __restrict__ w3,    // [1, 16]
    const float* __restrict__ b3,    // [1]
    float* __restrict__ out)         // [B, 1]
{
  const int L  = threadIdx.x;        // 0..255
  const int l  = L & 63;
  const int wv = L >> 6;             // wave 0..3
  const int r0 = blockIdx.x * ROWS;

  // ---------------- LDS (~18 KB) ----------------
  // Single in-place fp16 A-frag buffer; row = 24 halves (48 B, bank-clean).
  __shared__ __align__(16) _Float16 hfrag[2][64][24];  // [kt][fraglane][.] 6 KB
  __shared__ float xbuf[2][ROWS][68];
  __shared__ float ybuf1[ROWS][36];
  __shared__ float ybuf2[ROWS][20];

  // ---------------- W fragments (fp16, exp2-prescaled, registers) ----------
  half8 bf[3][2];
  {
    const int n0 = l & 15, q = l >> 4;
    const float gscale[3] = {-LOG2E, -LOG2E, 2.0f * LOG2E};
    #pragma unroll
    for (int gate = 0; gate < 3; ++gate) {
      const int c = gate * 64 + 16 * wv + n0;
      #pragma unroll
      for (int kt = 0; kt < 2; ++kt) {
        const float* p = w_hh + c * HID + kt * 32 + q * 8;
        half8 v;
        #pragma unroll
        for (int j = 0; j < 8; ++j) v[j] = (_Float16)(p[j] * gscale[gate]);
        bf[gate][kt] = v;
      }
    }
  }

  // ---------------- per-lane constants (prescaled) ----------------
  const int u  = 16 * wv + (l & 15);
  const int qq = l >> 4;
  const float wir = -LOG2E * w_ih[u];
  const float wiz = -LOG2E * w_ih[64 + u];
  const float win = 2.0f * LOG2E * w_ih[128 + u];
  const float br  = -LOG2E * (b_ih[u] + b_hh[u]);
  const float bz  = -LOG2E * (b_ih[64 + u] + b_hh[64 + u]);
  const float bni = 2.0f * LOG2E * b_ih[128 + u];
  const float bnh = 2.0f * LOG2E * b_hh[128 + u];
  float h[4] = {0.f, 0.f, 0.f, 0.f};

  const int wkt = u >> 5;
  const int wQ  = (u >> 3) & 3;
  const int wj  = u & 7;
  _Float16* hst = &hfrag[wkt][16 * wQ + 4 * qq][wj];  // + 24*r for row r

  // zero hfrag (h0 = 0 for all rows, both groups)
  for (int i = L; i < 2 * 64 * 24 / 2; i += THREADS) ((unsigned*)hfrag)[i] = 0u;

  const float* xblk = x + (size_t)r0 * SEQ;
  const int srow = L >> 4, stq = L & 15;

  // stage tb=0 into xbuf[0]
  {
    f32x4 v = *(const f32x4*)(xblk + (size_t)srow * SEQ + stq * 4);
    *(f32x4*)&xbuf[0][srow][stq * 4] = v;
  }

  // pipeline prologue: acc_G0(step 0) = W·h(0) = 0
  f32x4 aX0 = {0.f, 0.f, 0.f, 0.f}, aX1 = aX0, aX2 = aX0;

  // ---------------- scan: 2 phases per step ----------------
  for (int tb = 0; tb < NTB; ++tb) {
    const int par = tb & 1;
    const int tbn = (tb < NTB - 1) ? tb + 1 : tb;
    f32x4 xg = *(const f32x4*)(xblk + (size_t)srow * SEQ + tbn * 64 + stq * 4);

    #pragma unroll 1
    for (int s = 0; s < 64; ++s) {
      // ======== phase Y(s): gates_G0(s) via aX; MFMA(h_G1(s)) -> aY ========
      __syncthreads();
      half8 a0 = *(const half8*)&hfrag[0][l][0];
      half8 a1 = *(const half8*)&hfrag[1][l][0];
      float x0 = xbuf[par][4 * qq + 0][s];
      float x1 = xbuf[par][4 * qq + 1][s];
      #pragma unroll
      for (int r = 0; r < 2; ++r) {
        const float xt = (r == 0) ? x0 : x1;
        float rpp = aX0[r] + __fmaf_rn(xt, wir, br);
        float rr  = rcp_fast(1.0f + exp2_fast(rpp));
        float zpp = aX1[r] + __fmaf_rn(xt, wiz, bz);
        float zz  = rcp_fast(1.0f + exp2_fast(zpp));
        float npp = __fmaf_rn(rr, aX2[r] + bnh, __fmaf_rn(xt, win, bni));
        float nn  = __fmaf_rn(-2.0f, rcp_fast(exp2_fast(npp) + 1.0f), 1.0f);
        h[r] = __fmaf_rn(zz, h[r] - nn, nn);
        hst[24 * r] = (_Float16)h[r];   // store h_G0(s+1)
      }
      f32x4 aY0 = {0.f, 0.f, 0.f, 0.f}, aY1 = aY0, aY2 = aY0;
      aY0 = __builtin_amdgcn_mfma_f32_16x16x32_f16(a0, bf[0][0], aY0, 0, 0, 0);
      aY1 = __builtin_amdgcn_mfma_f32_16x16x32_f16(a0, bf[1][0], aY1, 0, 0, 0);
      aY2 = __builtin_amdgcn_mfma_f32_16x16x32_f16(a0, bf[2][0], aY2, 0, 0, 0);
      aY0 = __builtin_amdgcn_mfma_f32_16x16x32_f16(a1, bf[0][1], aY0, 0, 0, 0);
      aY1 = __builtin_amdgcn_mfma_f32_16x16x32_f16(a1, bf[1][1], aY1, 0, 0, 0);
      aY2 = __builtin_amdgcn_mfma_f32_16x16x32_f16(a1, bf[2][1], aY2, 0, 0, 0);

      // ======== phase X(s+1): gates_G1(s) via aY; MFMA(h_G0(s+1)) -> aX ====
      __syncthreads();
      a0 = *(const half8*)&hfrag[0][l][0];
      a1 = *(const half8*)&hfrag[1][l][0];
      float x2 = xbuf[par][4 * qq + 2][s];
      float x3 = xbuf[par][4 * qq + 3][s];
      #pragma unroll
      for (int r = 2; r < 4; ++r) {
        const float xt = (r == 2) ? x2 : x3;
        float rpp = aY0[r] + __fmaf_rn(xt, wir, br);
        float rr  = rcp_fast(1.0f + exp2_fast(rpp));
        float zpp = aY1[r] + __fmaf_rn(xt, wiz, bz);
        float zz  = rcp_fast(1.0f + exp2_fast(zpp));
        float npp = __fmaf_rn(rr, aY2[r] + bnh, __fmaf_rn(xt, win, bni));
        float nn  = __fmaf_rn(-2.0f, rcp_fast(exp2_fast(npp) + 1.0f), 1.0f);
        h[r] = __fmaf_rn(zz, h[r] - nn, nn);
        hst[24 * r] = (_Float16)h[r];   // store h_G1(s+1)
      }
      aX0 = (f32x4){0.f, 0.f, 0.f, 0.f}; aX1 = aX0; aX2 = aX0;
      aX0 = __builtin_amdgcn_mfma_f32_16x16x32_f16(a0, bf[0][0], aX0, 0, 0, 0);
      aX1 = __builtin_amdgcn_mfma_f32_16x16x32_f16(a0, bf[1][0], aX1, 0, 0, 0);
      aX2 = __builtin_amdgcn_mfma_f32_16x16x32_f16(a0, bf[2][0], aX2, 0, 0, 0);
      aX0 = __builtin_amdgcn_mfma_f32_16x16x32_f16(a1, bf[0][1], aX0, 0, 0, 0);
      aX1 = __builtin_amdgcn_mfma_f32_16x16x32_f16(a1, bf[1][1], aX1, 0, 0, 0);
      aX2 = __builtin_amdgcn_mfma_f32_16x16x32_f16(a1, bf[2][1], aX2, 0, 0, 0);
    }

    // stage next tb's x (consumers >= 1 barrier away)
    *(f32x4*)&xbuf[par ^ 1][srow][stq * 4] = xg;
  }

  // ---------------- MLP head: 64 -> 32 -> 16 -> 1 ----------------
  __syncthreads();
  #pragma unroll
  for (int r = 0; r < 4; ++r) xbuf[0][4 * qq + r][u] = h[r];  // h fp32 -> LDS
  __syncthreads();

  #pragma unroll
  for (int rep = 0; rep < 2; ++rep) {           // 16 rows x 32 outs = 512 tasks
    const int o = (L & 15) + 16 * rep;
    const int row = L >> 4;
    float a = b1[o];
    #pragma unroll
    for (int j4 = 0; j4 < 16; ++j4) {
      f32x4 wv4 = *(const f32x4*)&w1[o * 64 + 4 * j4];
      f32x4 hv  = *(const f32x4*)&xbuf[0][row][4 * j4];
      a += wv4[0] * hv[0] + wv4[1] * hv[1] + wv4[2] * hv[2] + wv4[3] * hv[3];
    }
    ybuf1[row][o] = (a > 0.0f) ? a : 0.01f * a;
  }
  __syncthreads();

  {
    const int o = L & 15;
    const int row = L >> 4;
    float a = b2[o];
    #pragma unroll
    for (int j4 = 0; j4 < 8; ++j4) {
      f32x4 wv4 = *(const f32x4*)&w2[o * 32 + 4 * j4];
      f32x4 yv  = *(const f32x4*)&ybuf1[row][4 * j4];
      a += wv4[0] * yv[0] + wv4[1] * yv[1] + wv4[2] * yv[2] + wv4[3] * yv[3];
    }
    ybuf2[row][o] = (a > 0.0f) ? a : 0.01f * a;
  }
  __syncthreads();

  if (L < ROWS) {
    float a = b3[0];
    #pragma unroll
    for (int j = 0; j < 16; ++j) a = __fmaf_rn(w3[j], ybuf2[L][j], a);
    out[r0 + L] = a;
  }
}

extern "C" void kernel_launch(void* const* d_in, const int* in_sizes, int n_in,
                              void* d_out, int out_size, void* d_ws, size_t ws_size,
                              hipStream_t stream) {
  const float* x    = (const float*)d_in[0];
  const float* w_ih = (const float*)d_in[1];
  const float* w_hh = (const float*)d_in[2];
  const float* b_ih = (const float*)d_in[3];
  const float* b_hh = (const float*)d_in[4];
  const float* w1   = (const float*)d_in[5];
  const float* b1   = (const float*)d_in[6];
  const float* w2   = (const float*)d_in[7];
  const float* b2   = (const float*)d_in[8];
  const float* w3   = (const float*)d_in[9];
  const float* b3   = (const float*)d_in[10];
  float* out = (float*)d_out;

  dim3 grid(BATCH / ROWS);  // 256 blocks x 4 waves x 16 rows — work-conserving
  dim3 block(THREADS);
  hipLaunchKernelGGL(gru_mfma, grid, block, 0, stream,
                     x, w_ih, w_hh, b_ih, b_hh, w1, b1, w2, b2, w3, b3, out);
}

// Round 11
// 373.956 us; speedup vs baseline: 1.4717x; 1.4717x over previous
//
#include <hip/hip_runtime.h>

// GRU_43387759624777 — Round 11: R9 slim step at ROWS=8 / 2 blocks/CU.
//
// R10 post-mortem: each barrier event at 1 block/CU costs ~350 cyc (confirmed
// R3->R5 and R9->R10); R9's 871 cyc/step = 453 issue + ~390 exposed latency,
// hideable only by a co-resident independent block. R6's ROWS=8 failure was an
// artifact of the fat 3-term bf16 step (4 b128 + 16 perms + 18 MFMA) and of
// exec-masked gate math (masked lanes still pay issue). Fixes here:
//  - ROWS=8, grid 512 -> 2 blocks/CU, 2 waves/SIMD (proven co-resident in R6).
//  - interleaved A-row map: batch row b -> A-row 4*(b>>1)+(b&1), so valid D
//    rows land in regs 0,1 of EVERY quad: all lanes do 2 rows' gates
//    (12 transc/wave-step, work-conserving), no masking, no redistribution.
//  - x transposed in LDS: xT[s][row] -> one ds_read_b64 per lane-step.
//
// Verified invariants (R3..R9): A-frag [m=lane&15][k=(lane>>4)*8+j]; C/D
// col=lane&15, row=(lane>>4)*4+reg; fp16 1-term MFMA + exp2-domain prescale
// (absmax 0.0 at R9/R10); h(A-row m, unit u) -> hfrag[u>>5][m+16*((u>>3)&3)][u&7].

#define HID 64
#define SEQ 1024
#define BATCH 4096
#define ROWS 8
#define THREADS 256
#define NTB (SEQ / 64)

typedef __attribute__((ext_vector_type(8))) _Float16 half8;
typedef __attribute__((ext_vector_type(4))) float f32x4;
typedef __attribute__((ext_vector_type(2))) float f32x2;

#define LOG2E 1.44269504088896340736f

__device__ __forceinline__ float rcp_fast(float x) { return __builtin_amdgcn_rcpf(x); }
__device__ __forceinline__ float exp2_fast(float x) { return __builtin_amdgcn_exp2f(x); }

__global__ __launch_bounds__(THREADS, 2) void gru_mfma(
    const float* __restrict__ x,     // [B, T]
    const float* __restrict__ w_ih,  // [192, 1]
    const float* __restrict__ w_hh,  // [192, 64]
    const float* __restrict__ b_ih,  // [192]
    const float* __restrict__ b_hh,  // [192]
    const float* __restrict__ w1,    // [32, 64]
    const float* __restrict__ b1,    // [32]
    const float* __restrict__ w2,    // [16, 32]
    const float* __restrict__ b2,    // [16]
    const float* __restrict__ w3,    // [1, 16]
    const float* __restrict__ b3,    // [1]
    float* __restrict__ out)         // [B, 1]
{
  const int L  = threadIdx.x;        // 0..255
  const int l  = L & 63;
  const int wv = L >> 6;             // wave 0..3
  const int r0 = blockIdx.x * ROWS;  // first batch row (512 blocks x 8 rows)

  // ---------------- LDS (~21 KB -> 2 blocks/CU) ----------------
  __shared__ __align__(16) _Float16 hfrag[2][2][64][24]; // dbuf A-frags, 12 KB
  __shared__ __align__(8) float xT[2][64][10];           // x transposed, 5 KB
  __shared__ float hb[ROWS][68];                         // head h staging
  __shared__ float ybuf1[ROWS][36];
  __shared__ float ybuf2[ROWS][20];

  // ---------------- W fragments (fp16, exp2-prescaled, registers) ----------
  half8 bf[3][2];
  {
    const int n0 = l & 15, q = l >> 4;
    const float gscale[3] = {-LOG2E, -LOG2E, 2.0f * LOG2E};
    #pragma unroll
    for (int gate = 0; gate < 3; ++gate) {
      const int c = gate * 64 + 16 * wv + n0;
      #pragma unroll
      for (int kt = 0; kt < 2; ++kt) {
        const float* p = w_hh + c * HID + kt * 32 + q * 8;
        half8 v;
        #pragma unroll
        for (int j = 0; j < 8; ++j) v[j] = (_Float16)(p[j] * gscale[gate]);
        bf[gate][kt] = v;
      }
    }
  }

  // ---------------- per-lane constants (prescaled) ----------------
  // Lane owns unit u = 16wv + (l&15) and BATCH rows 2qq, 2qq+1 (qq = l>>4),
  // which live at A-rows 4qq, 4qq+1 (interleaved map) = D regs 0,1 of its quad.
  const int u  = 16 * wv + (l & 15);
  const int qq = l >> 4;
  const float wir = -LOG2E * w_ih[u];
  const float wiz = -LOG2E * w_ih[64 + u];
  const float win = 2.0f * LOG2E * w_ih[128 + u];
  const float br  = -LOG2E * (b_ih[u] + b_hh[u]);
  const float bz  = -LOG2E * (b_ih[64 + u] + b_hh[64 + u]);
  const float bni = 2.0f * LOG2E * b_ih[128 + u];
  const float bnh = 2.0f * LOG2E * b_hh[128 + u];
  float h0 = 0.f, h1 = 0.f;

  // store target: (A-row m, unit u) -> hfrag[buf][u>>5][m + 16*((u>>3)&3)][u&7]
  const int wkt = u >> 5;
  const int wQ  = (u >> 3) & 3;
  const int wj  = u & 7;
  const int fl0 = 4 * qq + 16 * wQ;   // fraglane for m0 = 4qq (m1 = fl0+1)

  // zero hfrag (h0 = 0; A-rows {2,3 mod 4} stay zero forever)
  for (int i = L; i < 2 * 2 * 64 * 24 / 2; i += THREADS) ((unsigned*)hfrag)[i] = 0u;

  const float* xblk = x + (size_t)r0 * SEQ;
  const int srow = L >> 4, stq = L & 15;   // staging: 8 rows x 16 quads = 128

  if (L < 128) {  // stage tb=0, transposed
    f32x4 v = *(const f32x4*)(xblk + (size_t)srow * SEQ + stq * 4);
    #pragma unroll
    for (int i = 0; i < 4; ++i) xT[0][stq * 4 + i][srow] = v[i];
  }

  // ---------------- scan: one barrier per step ----------------
  for (int tb = 0; tb < NTB; ++tb) {
    const int par = tb & 1;
    const int tbn = (tb < NTB - 1) ? tb + 1 : tb;
    f32x4 xg = {0.f, 0.f, 0.f, 0.f};
    if (L < 128)  // prefetch next tb's x (64 steps of latency budget)
      xg = *(const f32x4*)(xblk + (size_t)srow * SEQ + tbn * 64 + stq * 4);

    #pragma unroll 2
    for (int s = 0; s < 64; ++s) {
      const int cur = s & 1, nxt = cur ^ 1;
      __syncthreads();  // prev step's hfrag writes (and this tb's xT) visible

      // ---- A-fragments: single fp16 plane, 2x ds_read_b128 ----
      half8 a0 = *(const half8*)&hfrag[cur][0][l][0];
      half8 a1 = *(const half8*)&hfrag[cur][1][l][0];

      // ---- x for this lane's 2 rows: one ds_read_b64 (broadcast) ----
      f32x2 xp = *(const f32x2*)&xT[par][s][2 * qq];

      // ---- MFMA: 3 gates x (kt0 -> kt1 chained), 6 total ----
      f32x4 acc0 = {0.f, 0.f, 0.f, 0.f};
      f32x4 acc1 = {0.f, 0.f, 0.f, 0.f};
      f32x4 acc2 = {0.f, 0.f, 0.f, 0.f};
      acc0 = __builtin_amdgcn_mfma_f32_16x16x32_f16(a0, bf[0][0], acc0, 0, 0, 0);
      acc1 = __builtin_amdgcn_mfma_f32_16x16x32_f16(a0, bf[1][0], acc1, 0, 0, 0);
      acc2 = __builtin_amdgcn_mfma_f32_16x16x32_f16(a0, bf[2][0], acc2, 0, 0, 0);
      acc0 = __builtin_amdgcn_mfma_f32_16x16x32_f16(a1, bf[0][1], acc0, 0, 0, 0);
      acc1 = __builtin_amdgcn_mfma_f32_16x16x32_f16(a1, bf[1][1], acc1, 0, 0, 0);
      acc2 = __builtin_amdgcn_mfma_f32_16x16x32_f16(a1, bf[2][1], acc2, 0, 0, 0);

      // ---- gates for 2 rows (regs 0,1 valid in every quad; 2,3 discarded) ----
      {
        float rpp = acc0[0] + __fmaf_rn(xp[0], wir, br);
        float rr  = rcp_fast(1.0f + exp2_fast(rpp));
        float zpp = acc1[0] + __fmaf_rn(xp[0], wiz, bz);
        float zz  = rcp_fast(1.0f + exp2_fast(zpp));
        float npp = __fmaf_rn(rr, acc2[0] + bnh, __fmaf_rn(xp[0], win, bni));
        float nn  = __fmaf_rn(-2.0f, rcp_fast(exp2_fast(npp) + 1.0f), 1.0f);
        h0 = __fmaf_rn(zz, h0 - nn, nn);
        hfrag[nxt][wkt][fl0][wj] = (_Float16)h0;
      }
      {
        float rpp = acc0[1] + __fmaf_rn(xp[1], wir, br);
        float rr  = rcp_fast(1.0f + exp2_fast(rpp));
        float zpp = acc1[1] + __fmaf_rn(xp[1], wiz, bz);
        float zz  = rcp_fast(1.0f + exp2_fast(zpp));
        float npp = __fmaf_rn(rr, acc2[1] + bnh, __fmaf_rn(xp[1], win, bni));
        float nn  = __fmaf_rn(-2.0f, rcp_fast(exp2_fast(npp) + 1.0f), 1.0f);
        h1 = __fmaf_rn(zz, h1 - nn, nn);
        hfrag[nxt][wkt][fl0 + 1][wj] = (_Float16)h1;
      }
    }

    if (L < 128) {  // stage next tb's x (consumers >= 1 barrier away)
      #pragma unroll
      for (int i = 0; i < 4; ++i) xT[par ^ 1][stq * 4 + i][srow] = xg[i];
    }
  }

  // ---------------- MLP head: 64 -> 32 -> 16 -> 1 ----------------
  __syncthreads();
  hb[2 * qq + 0][u] = h0;
  hb[2 * qq + 1][u] = h1;
  __syncthreads();

  {
    const int o = L & 31, row = L >> 5;          // 8 rows x 32 outs = 256 tasks
    float a = b1[o];
    #pragma unroll
    for (int j4 = 0; j4 < 16; ++j4) {
      f32x4 wv4 = *(const f32x4*)&w1[o * 64 + 4 * j4];
      f32x4 hv  = *(const f32x4*)&hb[row][4 * j4];
      a += wv4[0] * hv[0] + wv4[1] * hv[1] + wv4[2] * hv[2] + wv4[3] * hv[3];
    }
    ybuf1[row][o] = (a > 0.0f) ? a : 0.01f * a;
  }
  __syncthreads();

  if (L < 128) {
    const int o = L & 15, row = L >> 4;          // 8 rows x 16 outs = 128 tasks
    float a = b2[o];
    #pragma unroll
    for (int j4 = 0; j4 < 8; ++j4) {
      f32x4 wv4 = *(const f32x4*)&w2[o * 32 + 4 * j4];
      f32x4 yv  = *(const f32x4*)&ybuf1[row][4 * j4];
      a += wv4[0] * yv[0] + wv4[1] * yv[1] + wv4[2] * yv[2] + wv4[3] * yv[3];
    }
    ybuf2[row][o] = (a > 0.0f) ? a : 0.01f * a;
  }
  __syncthreads();

  if (L < ROWS) {
    float a = b3[0];
    #pragma unroll
    for (int j = 0; j < 16; ++j) a = __fmaf_rn(w3[j], ybuf2[L][j], a);
    out[r0 + L] = a;
  }
}

extern "C" void kernel_launch(void* const* d_in, const int* in_sizes, int n_in,
                              void* d_out, int out_size, void* d_ws, size_t ws_size,
                              hipStream_t stream) {
  const float* x    = (const float*)d_in[0];
  const float* w_ih = (const float*)d_in[1];
  const float* w_hh = (const float*)d_in[2];
  const float* b_ih = (const float*)d_in[3];
  const float* b_hh = (const float*)d_in[4];
  const float* w1   = (const float*)d_in[5];
  const float* b1   = (const float*)d_in[6];
  const float* w2   = (const float*)d_in[7];
  const float* b2   = (const float*)d_in[8];
  const float* w3   = (const float*)d_in[9];
  const float* b3   = (const float*)d_in[10];
  float* out = (float*)d_out;

  dim3 grid(BATCH / ROWS);  // 512 blocks x 4 waves x 8 rows -> 2 blocks/CU
  dim3 block(THREADS);
  hipLaunchKernelGGL(gru_mfma, grid, block, 0, stream,
                     x, w_ih, w_hh, b_ih, b_hh, w1, b1, w2, b2, w3, b3, out);
}